// Round 6
// baseline (215.737 us; speedup 1.0000x reference)
//
#include <hip/hip_runtime.h>

#define N_NODES   50000
#define N_EDGES   800000
#define NEG_SLOPE 0.2f
#define NBKT      256          // coarse buckets
#define NPB       196          // nodes per bucket (196*256 = 50176 >= 50000)
#define EPB       3125         // edges per binscatter block (800000/256)
#define CAP       4096         // fixed bucket capacity (true ~3136 +- 56; 17 sigma)
#define G1BLK     782          // gemm1 blocks: ceil(50000/64)

typedef float f32x2 __attribute__((ext_vector_type(2)));
typedef float f32x4 __attribute__((ext_vector_type(4)));

__device__ __forceinline__ float leaky(float x) {
    return x > 0.f ? x : x * NEG_SLOPE;
}

__device__ __forceinline__ unsigned short f2bf(float f) {   // RNE pack
    unsigned int u = __float_as_uint(f);
    unsigned int r = (u + 0x7FFFu + ((u >> 16) & 1u)) >> 16;
    return (unsigned short)r;
}

__device__ __forceinline__ unsigned int pack2bf(float a, float b) {
    return (unsigned int)f2bf(a) | ((unsigned int)f2bf(b) << 16);
}

__device__ __forceinline__ f32x2 bf2x2(unsigned int p) {    // packed bf16x2 -> 2 f32
    f32x2 r;
    r.x = __uint_as_float(p << 16);
    r.y = __uint_as_float(p & 0xFFFF0000u);
    return r;
}

__device__ __forceinline__ f32x2 lo2(f32x4 v) { return __builtin_shufflevector(v, v, 0, 1); }
__device__ __forceinline__ f32x2 hi2(f32x4 v) { return __builtin_shufflevector(v, v, 2, 3); }

// acc += broadcast(a.lo) * w     -- one v_pk_fma_f32 = 2 fp32 FMAs
__device__ __forceinline__ void pkfma_lo(f32x2& acc, f32x2 a, f32x2 w) {
    asm("v_pk_fma_f32 %0, %1, %2, %0 op_sel:[0,0,0] op_sel_hi:[0,1,1]"
        : "+v"(acc) : "v"(a), "v"(w));
}
// acc += broadcast(a.hi) * w
__device__ __forceinline__ void pkfma_hi(f32x2& acc, f32x2 a, f32x2 w) {
    asm("v_pk_fma_f32 %0, %1, %2, %0 op_sel:[1,0,0] op_sel_hi:[1,1,1]"
        : "+v"(acc) : "v"(a), "v"(w));
}
// pair whose lo word is x; hi word intentionally undefined (only lo is read via op_sel)
__device__ __forceinline__ f32x2 plow(float x) {
    f32x2 r;
    asm("" : "=v"(r));
    r.x = x;
    return r;
}

// ---------------- FAT kernel: blocks 0..255 binscatter, rest gemm1 ----------------
// gemm1: 64x128 block tile, 8x4 register tile/thread, bf16 LDS, pk_fma math. 48 KB overlay.
__global__ __launch_bounds__(256) void k_bin_gemm1(
    // binscatter args
    const int* __restrict__ src, const int* __restrict__ dst,
    int* __restrict__ cursor_g, unsigned int* __restrict__ binned,
    // gemm1 args
    const float* __restrict__ x, const float* __restrict__ W1,
    const float* __restrict__ a_src, const float* __restrict__ a_dst,
    unsigned short* __restrict__ h1b, float* __restrict__ al_src,
    float* __restrict__ al_dst)
{
    __shared__ __align__(16) unsigned char smem[49152];   // 48 KB overlay
    const int tid = threadIdx.x;

    if (blockIdx.x < NBKT) {
        // ---- binscatter with in-LDS histogram + global range reservation ----
        int* dstc = (int*)smem;               // 3125 ints (12.5 KB): cached dst
        int* cnt  = (int*)(smem + 12512);     // 256 ints
        int* cur  = (int*)(smem + 13536);     // 256 ints
        const int blk = blockIdx.x;
        const int e0  = blk * EPB;
        cnt[tid] = 0;
        __syncthreads();
        for (int j = tid; j < EPB; j += 256) {
            int d = dst[e0 + j];
            dstc[j] = d;
            atomicAdd(&cnt[d / NPB], 1);
        }
        __syncthreads();
        const int c = cnt[tid];
        int base = c ? atomicAdd(&cursor_g[tid], c) : 0;   // reserve range
        cur[tid] = tid * CAP + base;
        __syncthreads();
        for (int j = tid; j < EPB; j += 256) {
            int d   = dstc[j];
            int bkt = d / NPB;
            int dl  = d - bkt * NPB;
            int pos = atomicAdd(&cur[bkt], 1);
            binned[pos] = (unsigned int)src[e0 + j] | ((unsigned int)dl << 18);
        }
        return;
    }

    // ---- gemm1: 64 rows x 128 cols, 8x4 per thread, bf16 LDS, packed-f32 FMA ----
    uint2* xs = (uint2*)smem;                 // 16 KB: [row][g], g = 4-k granule
    uint2* ws = (uint2*)(smem + 16384);       // 32 KB: [k][cg], cg = 4-col granule
    const int bid  = (int)blockIdx.x - NBKT;
    const int row0 = bid * 64;
    const int tc   = tid & 31;                // col granule: cols tc*4 .. +3
    const int tr   = tid >> 5;                // row group: rows tr*8 .. +7
    const float4* x4  = (const float4*)x;
    const float4* W14 = (const float4*)W1;

    #pragma unroll
    for (int p = 0; p < 8; ++p) {             // x tile: 64 rows x 32 granules
        int i = tid + p * 256;
        int r = i >> 5, g = i & 31;
        int gr = row0 + r; if (gr > N_NODES - 1) gr = N_NODES - 1;
        float4 v = x4[gr * 32 + g];
        xs[r * 32 + g] = make_uint2(pack2bf(v.x, v.y), pack2bf(v.z, v.w));
    }
    #pragma unroll
    for (int p = 0; p < 16; ++p) {            // W: 128 k x 32 col-granules
        int i = tid + p * 256;
        int k = i >> 5, cg = i & 31;
        float4 v = W14[k * 32 + cg];
        ws[k * 32 + cg] = make_uint2(pack2bf(v.x, v.y), pack2bf(v.z, v.w));
    }
    __syncthreads();

    f32x2 acc[8][2];                          // [row][(c0,c1)|(c2,c3)]
    #pragma unroll
    for (int i = 0; i < 8; ++i) {
        acc[i][0] = (f32x2){0.f, 0.f};
        acc[i][1] = (f32x2){0.f, 0.f};
    }

    for (int k4 = 0; k4 < 32; ++k4) {         // 4 k per iteration
        f32x2 aP[8][2];                       // [row][(k0,k1)|(k2,k3)]
        #pragma unroll
        for (int i = 0; i < 8; ++i) {
            uint2 q = xs[(tr * 8 + i) * 32 + k4];
            aP[i][0] = bf2x2(q.x);
            aP[i][1] = bf2x2(q.y);
        }
        #pragma unroll
        for (int kk = 0; kk < 4; ++kk) {
            uint2 qw = ws[(k4 * 4 + kk) * 32 + tc];
            f32x2 wlo = bf2x2(qw.x);
            f32x2 whi = bf2x2(qw.y);
            #pragma unroll
            for (int i = 0; i < 8; ++i) {
                f32x2 ap = aP[i][kk >> 1];
                if ((kk & 1) == 0) {
                    pkfma_lo(acc[i][0], ap, wlo);
                    pkfma_lo(acc[i][1], ap, whi);
                } else {
                    pkfma_hi(acc[i][0], ap, wlo);
                    pkfma_hi(acc[i][1], ap, whi);
                }
            }
        }
    }

    const int head = tc >> 2;
    const float4 as4 = ((const float4*)a_src)[tc];
    const float4 ad4 = ((const float4*)a_dst)[tc];
    #pragma unroll
    for (int i = 0; i < 8; ++i) {
        int r = row0 + tr * 8 + i;
        float s = acc[i][0].x * as4.x + acc[i][0].y * as4.y
                + acc[i][1].x * as4.z + acc[i][1].y * as4.w;
        float d = acc[i][0].x * ad4.x + acc[i][0].y * ad4.y
                + acc[i][1].x * ad4.z + acc[i][1].y * ad4.w;
        s += __shfl_xor(s, 1); s += __shfl_xor(s, 2);
        d += __shfl_xor(d, 1); d += __shfl_xor(d, 2);
        if (r < N_NODES) {
            ((uint2*)h1b)[r * 32 + tc] =
                make_uint2(pack2bf(acc[i][0].x, acc[i][0].y),
                           pack2bf(acc[i][1].x, acc[i][1].y));
            if ((tc & 3) == 0) {
                al_src[r * 8 + head] = s;
                al_dst[r * 8 + head] = d;
            }
        }
    }
}

// ---------------- fine CSR per bucket (1024 thr, wave-shuffle scan) ----------------
__global__ __launch_bounds__(1024) void k_csr_fine(const unsigned int* __restrict__ binned,
                                                   const int* __restrict__ cursor_g,
                                                   int* __restrict__ row_beg,
                                                   int* __restrict__ row_end,
                                                   int* __restrict__ csr) {
    __shared__ int cnt[256];
    __shared__ int cur[256];
    __shared__ int wsum[4];
    const int b = blockIdx.x, tid = threadIdx.x;
    const int start = b * CAP;
    const int nE    = cursor_g[b];
    if (tid < 256) cnt[tid] = 0;
    __syncthreads();
    for (int j = tid; j < nE; j += 1024)
        atomicAdd(&cnt[(binned[start + j] >> 18) & 255], 1);
    __syncthreads();
    int v = 0;
    if (tid < 256) v = cnt[tid];
    int sv = v;                                // wave-inclusive scan (64 lanes)
    #pragma unroll
    for (int off = 1; off < 64; off <<= 1) {
        int t = __shfl_up(sv, off);
        if ((tid & 63) >= off) sv += t;
    }
    if (tid < 256 && (tid & 63) == 63) wsum[tid >> 6] = sv;
    __syncthreads();
    if (tid < 256) {
        int w = tid >> 6;
        int add = 0;
        #pragma unroll
        for (int i = 0; i < 3; ++i) add += (i < w) ? wsum[i] : 0;
        int excl = sv + add - v;
        cur[tid] = excl;
        const int node = b * NPB + tid;
        if (tid < NPB && node < N_NODES) {
            row_beg[node] = start + excl;
            row_end[node] = start + excl + v;
        }
    }
    __syncthreads();
    for (int j = tid; j < nE; j += 1024) {
        unsigned int p = binned[start + j];
        int dl  = (p >> 18) & 255;
        int pos = start + atomicAdd(&cur[dl], 1);
        csr[pos] = (int)(p & 0x3FFFFu);
    }
}

// ---------------- agg1+gemm2 fused: gather (guarded 4-wide), then gemm2 with W2 in REGISTERS ----------------
// No W2 LDS, no barrier at all; only per-wave 2 KB h2row scratch.
__global__ __launch_bounds__(256) void k_agg1g2(
    const unsigned short* __restrict__ h1b, const float* __restrict__ al_src,
    const float* __restrict__ al_dst, const int* __restrict__ row_beg,
    const int* __restrict__ row_end, const int* __restrict__ csr_src,
    const float* __restrict__ b1, const float* __restrict__ W2,
    const float* __restrict__ a_src2, const float* __restrict__ a_dst2,
    unsigned short* __restrict__ t2b, float* __restrict__ alS2,
    float* __restrict__ alD2)
{
    __shared__ __align__(16) float h2row[4][128];   // 2 KB, per-wave scratch
    const int tid  = threadIdx.x;
    const int wv   = tid >> 6;
    const int n    = blockIdx.x * 4 + wv;
    const int l    = tid & 63;
    const int slot = l >> 4;
    const int f2   = l & 15;
    const int head = f2 >> 1;
    const uint4* h1q = (const uint4*)h1b;    // 16 B = 8 bf16 feats

    const float alD = al_dst[n * 8 + head];
    const int beg = row_beg[n], end = row_end[n];

    float denom = 0.f;
    f32x2 a01 = {0.f, 0.f}, a23 = {0.f, 0.f}, a45 = {0.f, 0.f}, a67 = {0.f, 0.f};

    if (slot == 0) {   // self loop
        float w = __expf(leaky(al_src[n * 8 + head] + alD));
        uint4 q = h1q[n * 16 + f2];
        denom = w;
        f32x2 wp = plow(w);
        pkfma_lo(a01, wp, bf2x2(q.x));
        pkfma_lo(a23, wp, bf2x2(q.y));
        pkfma_lo(a45, wp, bf2x2(q.z));
        pkfma_lo(a67, wp, bf2x2(q.w));
    }

    // guarded 4-wide gather: 4 independent csr loads -> 8 independent gathers per iter
    for (int j = beg + slot; j < end; j += 16) {
        const int e1 = (j + 4  < end) ? j + 4  : j;
        const int e2 = (j + 8  < end) ? j + 8  : j;
        const int e3 = (j + 12 < end) ? j + 12 : j;
        int s0 = csr_src[j];
        int s1 = csr_src[e1];
        int s2 = csr_src[e2];
        int s3 = csr_src[e3];
        float l0 = al_src[s0 * 8 + head];
        float l1 = al_src[s1 * 8 + head];
        float l2 = al_src[s2 * 8 + head];
        float l3 = al_src[s3 * 8 + head];
        uint4 q0 = h1q[s0 * 16 + f2];
        uint4 q1 = h1q[s1 * 16 + f2];
        uint4 q2 = h1q[s2 * 16 + f2];
        uint4 q3 = h1q[s3 * 16 + f2];
        float w0 = __expf(leaky(l0 + alD));
        float w1 = __expf(leaky(l1 + alD)); w1 = (e1 != j) ? w1 : 0.f;
        float w2 = __expf(leaky(l2 + alD)); w2 = (e2 != j) ? w2 : 0.f;
        float w3 = __expf(leaky(l3 + alD)); w3 = (e3 != j) ? w3 : 0.f;
        denom += (w0 + w1) + (w2 + w3);
        f32x2 wA; wA.x = w0; wA.y = w1;
        f32x2 wB; wB.x = w2; wB.y = w3;
        pkfma_lo(a01, wA, bf2x2(q0.x));
        pkfma_lo(a23, wA, bf2x2(q0.y));
        pkfma_lo(a45, wA, bf2x2(q0.z));
        pkfma_lo(a67, wA, bf2x2(q0.w));
        pkfma_hi(a01, wA, bf2x2(q1.x));
        pkfma_hi(a23, wA, bf2x2(q1.y));
        pkfma_hi(a45, wA, bf2x2(q1.z));
        pkfma_hi(a67, wA, bf2x2(q1.w));
        pkfma_lo(a01, wB, bf2x2(q2.x));
        pkfma_lo(a23, wB, bf2x2(q2.y));
        pkfma_lo(a45, wB, bf2x2(q2.z));
        pkfma_lo(a67, wB, bf2x2(q2.w));
        pkfma_hi(a01, wB, bf2x2(q3.x));
        pkfma_hi(a23, wB, bf2x2(q3.y));
        pkfma_hi(a45, wB, bf2x2(q3.z));
        pkfma_hi(a67, wB, bf2x2(q3.w));
    }

    // W2 fragment -> registers (16 KB table, L2-hot; 16 coalesced b128 loads/lane)
    const int cg = l & 7;
    const int kg = l >> 3;
    f32x4 wf[16];
    {
        const f32x4* W2v = (const f32x4*)W2;
        #pragma unroll
        for (int t = 0; t < 16; ++t)
            wf[t] = W2v[(kg * 16 + t) * 8 + cg];
    }

    #pragma unroll
    for (int off = 16; off <= 32; off <<= 1) {
        a01.x += __shfl_xor(a01.x, off); a01.y += __shfl_xor(a01.y, off);
        a23.x += __shfl_xor(a23.x, off); a23.y += __shfl_xor(a23.y, off);
        a45.x += __shfl_xor(a45.x, off); a45.y += __shfl_xor(a45.y, off);
        a67.x += __shfl_xor(a67.x, off); a67.y += __shfl_xor(a67.y, off);
        denom += __shfl_xor(denom, off);
    }

    // h2 row (bias + ELU) — all lanes compute; slot 0 writes to per-wave LDS
    {
        const float4 bA = ((const float4*)b1)[f2 * 2];
        const float4 bB = ((const float4*)b1)[f2 * 2 + 1];
        float inv = 1.f / denom;
        float o[8];
        o[0] = a01.x * inv + bA.x; o[1] = a01.y * inv + bA.y;
        o[2] = a23.x * inv + bA.z; o[3] = a23.y * inv + bA.w;
        o[4] = a45.x * inv + bB.x; o[5] = a45.y * inv + bB.y;
        o[6] = a67.x * inv + bB.z; o[7] = a67.y * inv + bB.w;
        #pragma unroll
        for (int i = 0; i < 8; ++i) o[i] = o[i] > 0.f ? o[i] : __expf(o[i]) - 1.f;
        if (slot == 0) {
            *(float4*)&h2row[wv][f2 * 8]     = make_float4(o[0], o[1], o[2], o[3]);
            *(float4*)&h2row[wv][f2 * 8 + 4] = make_float4(o[4], o[5], o[6], o[7]);
        }
    }
    // no barrier: h2row[wv] written and read by the same wave

    // fused gemm2: lane = (kg: 16 ks, cg: classes cg*4..+3), W frag in regs
    const float* hrow = h2row[wv];
    f32x4 hv[4];
    #pragma unroll
    for (int t = 0; t < 4; ++t)
        hv[t] = *(const f32x4*)&hrow[kg * 16 + t * 4];
    f32x2 s01 = {0.f, 0.f}, s23 = {0.f, 0.f};
    #pragma unroll
    for (int t = 0; t < 4; ++t) {
        f32x2 hlo = lo2(hv[t]);
        f32x2 hhi = hi2(hv[t]);
        #pragma unroll
        for (int u = 0; u < 4; ++u) {
            f32x4 w4 = wf[t * 4 + u];
            f32x2 wlo = lo2(w4);
            f32x2 whi = hi2(w4);
            if (u == 0)      { pkfma_lo(s01, hlo, wlo); pkfma_lo(s23, hlo, whi); }
            else if (u == 1) { pkfma_hi(s01, hlo, wlo); pkfma_hi(s23, hlo, whi); }
            else if (u == 2) { pkfma_lo(s01, hhi, wlo); pkfma_lo(s23, hhi, whi); }
            else             { pkfma_hi(s01, hhi, wlo); pkfma_hi(s23, hhi, whi); }
        }
    }
    #pragma unroll
    for (int off = 8; off <= 32; off <<= 1) {        // reduce over kg (bits 3..5)
        s01.x += __shfl_xor(s01.x, off); s01.y += __shfl_xor(s01.y, off);
        s23.x += __shfl_xor(s23.x, off); s23.y += __shfl_xor(s23.y, off);
    }

    if (l < 8)                                       // kg==0 lanes: 8 x 8 B = full t2 row
        ((uint2*)t2b)[n * 8 + cg] =
            make_uint2(pack2bf(s01.x, s01.y), pack2bf(s23.x, s23.y));

    const float4 as2 = ((const float4*)a_src2)[cg];
    const float4 ad2 = ((const float4*)a_dst2)[cg];
    float s2 = s01.x * as2.x + s01.y * as2.y + s23.x * as2.z + s23.y * as2.w;
    float d2 = s01.x * ad2.x + s01.y * ad2.y + s23.x * ad2.z + s23.y * ad2.w;
    #pragma unroll
    for (int off = 1; off <= 4; off <<= 1) {         // reduce over cg (bits 0..2)
        s2 += __shfl_xor(s2, off);
        d2 += __shfl_xor(d2, off);
    }
    if (l == 0) {
        alS2[n] = s2;
        alD2[n] = d2;
    }
}

// ---------------- agg2: wave/node, 8 slots x 8 lanes x 8B, guarded 4-wide, pk_fma ----------------
__global__ __launch_bounds__(256) void k_agg2(
    const unsigned short* __restrict__ t2b, const float* __restrict__ al_src,
    const float* __restrict__ al_dst, const int* __restrict__ row_beg,
    const int* __restrict__ row_end, const int* __restrict__ csr_src,
    const float* __restrict__ b2, float* __restrict__ out)
{
    const int n = blockIdx.x * 4 + (threadIdx.x >> 6);
    const int l = threadIdx.x & 63;
    const int slot = l >> 3;          // 8 edge slots
    const int f4   = l & 7;           // 4 classes per lane (uint2 of bf16x2)
    const uint2* t2u = (const uint2*)t2b;   // 8 B = 4 bf16

    const float alD = al_dst[n];
    const int beg = row_beg[n], end = row_end[n];
    float denom = 0.f;
    f32x2 a01 = {0.f, 0.f}, a23 = {0.f, 0.f};
    if (slot == 0) {                  // self loop
        float w = __expf(leaky(al_src[n] + alD));
        uint2 q = t2u[n * 8 + f4];
        denom = w;
        f32x2 wp = plow(w);
        pkfma_lo(a01, wp, bf2x2(q.x));
        pkfma_lo(a23, wp, bf2x2(q.y));
    }
    for (int j = beg + slot; j < end; j += 32) {   // guarded 4-wide
        const int e1 = (j + 8  < end) ? j + 8  : j;
        const int e2 = (j + 16 < end) ? j + 16 : j;
        const int e3 = (j + 24 < end) ? j + 24 : j;
        int s0 = csr_src[j];
        int s1 = csr_src[e1];
        int s2 = csr_src[e2];
        int s3 = csr_src[e3];
        float l0 = al_src[s0];
        float l1 = al_src[s1];
        float l2 = al_src[s2];
        float l3 = al_src[s3];
        uint2 q0 = t2u[s0 * 8 + f4];
        uint2 q1 = t2u[s1 * 8 + f4];
        uint2 q2 = t2u[s2 * 8 + f4];
        uint2 q3 = t2u[s3 * 8 + f4];
        float w0 = __expf(leaky(l0 + alD));
        float w1 = __expf(leaky(l1 + alD)); w1 = (e1 != j) ? w1 : 0.f;
        float w2 = __expf(leaky(l2 + alD)); w2 = (e2 != j) ? w2 : 0.f;
        float w3 = __expf(leaky(l3 + alD)); w3 = (e3 != j) ? w3 : 0.f;
        denom += (w0 + w1) + (w2 + w3);
        f32x2 wA; wA.x = w0; wA.y = w1;
        f32x2 wB; wB.x = w2; wB.y = w3;
        pkfma_lo(a01, wA, bf2x2(q0.x));
        pkfma_lo(a23, wA, bf2x2(q0.y));
        pkfma_hi(a01, wA, bf2x2(q1.x));
        pkfma_hi(a23, wA, bf2x2(q1.y));
        pkfma_lo(a01, wB, bf2x2(q2.x));
        pkfma_lo(a23, wB, bf2x2(q2.y));
        pkfma_hi(a01, wB, bf2x2(q3.x));
        pkfma_hi(a23, wB, bf2x2(q3.y));
    }
    // reduce over the 8 slots (lane bits 3,4,5)
    #pragma unroll
    for (int off = 8; off <= 32; off <<= 1) {
        a01.x += __shfl_xor(a01.x, off); a01.y += __shfl_xor(a01.y, off);
        a23.x += __shfl_xor(a23.x, off); a23.y += __shfl_xor(a23.y, off);
        denom += __shfl_xor(denom, off);
    }

    const float4 bb = ((const float4*)b2)[f4];
    float inv = 1.f / denom;
    float o0 = a01.x * inv + bb.x;
    float o1 = a01.y * inv + bb.y;
    float o2 = a23.x * inv + bb.z;
    float o3 = a23.y * inv + bb.w;
    // log_softmax over 32 classes (8 lanes x 4 classes; lane bits 0..2)
    float m = fmaxf(fmaxf(o0, o1), fmaxf(o2, o3));
    for (int off = 1; off <= 4; off <<= 1) m = fmaxf(m, __shfl_xor(m, off));
    float ssum = __expf(o0 - m) + __expf(o1 - m) + __expf(o2 - m) + __expf(o3 - m);
    for (int off = 1; off <= 4; off <<= 1) ssum += __shfl_xor(ssum, off);
    float lg = m + __logf(ssum);
    if (slot == 0)
        ((float4*)out)[n * 8 + f4] = make_float4(o0 - lg, o1 - lg, o2 - lg, o3 - lg);
}

extern "C" void kernel_launch(void* const* d_in, const int* in_sizes, int n_in,
                              void* d_out, int out_size, void* d_ws, size_t ws_size,
                              hipStream_t stream) {
    const float* x      = (const float*)d_in[0];
    const int*   src    = (const int*)d_in[1];
    const int*   dst    = (const int*)d_in[2];
    const float* W1     = (const float*)d_in[3];
    const float* a_src1 = (const float*)d_in[4];
    const float* a_dst1 = (const float*)d_in[5];
    const float* b1     = (const float*)d_in[6];
    const float* W2     = (const float*)d_in[7];
    const float* a_src2 = (const float*)d_in[8];
    const float* a_dst2 = (const float*)d_in[9];
    const float* b2     = (const float*)d_in[10];
    float* out = (float*)d_out;

    char* ws = (char*)d_ws;
    size_t off = 0;
    auto alloc = [&](size_t bytes) {
        void* p = ws + off;
        off += (bytes + 255) & ~(size_t)255;
        return p;
    };
    unsigned short* h1b = (unsigned short*)alloc((size_t)N_NODES * 128 * 2);
    unsigned short* t2b = (unsigned short*)alloc((size_t)N_NODES * 32 * 2);
    float* alS1    = (float*)alloc((size_t)N_NODES * 8 * 4);
    float* alD1    = (float*)alloc((size_t)N_NODES * 8 * 4);
    float* alS2    = (float*)alloc((size_t)N_NODES * 4);
    float* alD2    = (float*)alloc((size_t)N_NODES * 4);
    int*   row_beg = (int*)alloc((size_t)N_NODES * 4);
    int*   row_end = (int*)alloc((size_t)N_NODES * 4);
    int*   csr     = (int*)alloc((size_t)NBKT * CAP * 4);      // 4 MB padded
    unsigned int* binned = (unsigned int*)alloc((size_t)NBKT * CAP * 4);  // 4 MB
    int*   cursor  = (int*)alloc((size_t)NBKT * 4);
    (void)ws_size; (void)in_sizes; (void)n_in; (void)out_size;

    hipMemsetAsync(cursor, 0, (size_t)NBKT * 4, stream);
    k_bin_gemm1<<<NBKT + G1BLK, 256, 0, stream>>>(
        src, dst, cursor, binned,
        x, W1, a_src1, a_dst1, h1b, alS1, alD1);
    k_csr_fine<<<NBKT, 1024, 0, stream>>>(binned, cursor, row_beg, row_end, csr);
    k_agg1g2<<<N_NODES / 4, 256, 0, stream>>>(
        h1b, alS1, alD1, row_beg, row_end, csr,
        b1, W2, a_src2, a_dst2, t2b, alS2, alD2);
    k_agg2<<<N_NODES / 4, 256, 0, stream>>>(t2b, alS2, alD2, row_beg, row_end, csr, b2, out);
}

// Round 7
// 199.704 us; speedup vs baseline: 1.0803x; 1.0803x over previous
//
#include <hip/hip_runtime.h>

#define N_NODES   50000
#define N_EDGES   800000
#define NEG_SLOPE 0.2f
#define NBKT      256          // coarse buckets
#define NPB       196          // nodes per bucket (196*256 = 50176 >= 50000)
#define EPB       3125         // edges per binscatter block (800000/256)
#define CAP       4096         // fixed bucket capacity (true ~3136 +- 56; 17 sigma)
#define G1BLK     782          // gemm1 blocks: ceil(50000/64)

typedef float f32x2 __attribute__((ext_vector_type(2)));
typedef float f32x4 __attribute__((ext_vector_type(4)));

__device__ __forceinline__ float leaky(float x) {
    return x > 0.f ? x : x * NEG_SLOPE;
}

__device__ __forceinline__ unsigned short f2bf(float f) {   // RNE pack
    unsigned int u = __float_as_uint(f);
    unsigned int r = (u + 0x7FFFu + ((u >> 16) & 1u)) >> 16;
    return (unsigned short)r;
}

__device__ __forceinline__ unsigned int pack2bf(float a, float b) {
    return (unsigned int)f2bf(a) | ((unsigned int)f2bf(b) << 16);
}

__device__ __forceinline__ f32x2 bf2x2(unsigned int p) {    // packed bf16x2 -> 2 f32
    f32x2 r;
    r.x = __uint_as_float(p << 16);
    r.y = __uint_as_float(p & 0xFFFF0000u);
    return r;
}

__device__ __forceinline__ f32x2 lo2(f32x4 v) { return __builtin_shufflevector(v, v, 0, 1); }
__device__ __forceinline__ f32x2 hi2(f32x4 v) { return __builtin_shufflevector(v, v, 2, 3); }

// acc += broadcast(a.lo) * w     -- one v_pk_fma_f32 = 2 fp32 FMAs
__device__ __forceinline__ void pkfma_lo(f32x2& acc, f32x2 a, f32x2 w) {
    asm("v_pk_fma_f32 %0, %1, %2, %0 op_sel:[0,0,0] op_sel_hi:[0,1,1]"
        : "+v"(acc) : "v"(a), "v"(w));
}
// acc += broadcast(a.hi) * w
__device__ __forceinline__ void pkfma_hi(f32x2& acc, f32x2 a, f32x2 w) {
    asm("v_pk_fma_f32 %0, %1, %2, %0 op_sel:[1,0,0] op_sel_hi:[1,1,1]"
        : "+v"(acc) : "v"(a), "v"(w));
}
// pair whose lo word is x; hi word intentionally undefined (only lo is read via op_sel)
__device__ __forceinline__ f32x2 plow(float x) {
    f32x2 r;
    asm("" : "=v"(r));
    r.x = x;
    return r;
}

// ---------------- FAT kernel: blocks 0..255 binscatter, rest gemm1 ----------------
// gemm1: 64x128 tile, K-tiled W staging (32 KB LDS total -> 5 blocks/CU).
__global__ __launch_bounds__(256) void k_bin_gemm1(
    // binscatter args
    const int* __restrict__ src, const int* __restrict__ dst,
    int* __restrict__ cursor_g, unsigned int* __restrict__ binned,
    // gemm1 args
    const float* __restrict__ x, const float* __restrict__ W1,
    const float* __restrict__ a_src, const float* __restrict__ a_dst,
    unsigned short* __restrict__ h1b, float* __restrict__ al_src,
    float* __restrict__ al_dst)
{
    __shared__ __align__(16) unsigned char smem[32768];   // 32 KB overlay
    const int tid = threadIdx.x;

    if (blockIdx.x < NBKT) {
        // ---- binscatter with in-LDS histogram + global range reservation ----
        int* dstc = (int*)smem;               // 3125 ints (12.5 KB): cached dst
        int* cnt  = (int*)(smem + 12512);     // 256 ints
        int* cur  = (int*)(smem + 13536);     // 256 ints
        const int blk = blockIdx.x;
        const int e0  = blk * EPB;
        cnt[tid] = 0;
        __syncthreads();
        for (int j = tid; j < EPB; j += 256) {
            int d = dst[e0 + j];
            dstc[j] = d;
            atomicAdd(&cnt[d / NPB], 1);
        }
        __syncthreads();
        const int c = cnt[tid];
        int base = c ? atomicAdd(&cursor_g[tid], c) : 0;   // reserve range
        cur[tid] = tid * CAP + base;
        __syncthreads();
        for (int j = tid; j < EPB; j += 256) {
            int d   = dstc[j];
            int bkt = d / NPB;
            int dl  = d - bkt * NPB;
            int pos = atomicAdd(&cur[bkt], 1);
            binned[pos] = (unsigned int)src[e0 + j] | ((unsigned int)dl << 18);
        }
        return;
    }

    // ---- gemm1: 64 rows x 128 cols, 8x4 per thread, bf16 LDS, packed-f32 FMA ----
    uint2* xs = (uint2*)smem;                 // 16 KB: [row][g], g = 4-k granule, full K
    uint2* ws = (uint2*)(smem + 16384);       // 16 KB: [k_local 0..63][cg], K-half staged
    const int bid  = (int)blockIdx.x - NBKT;
    const int row0 = bid * 64;
    const int tc   = tid & 31;                // col granule: cols tc*4 .. +3
    const int tr   = tid >> 5;                // row group: rows tr*8 .. +7
    const float4* x4  = (const float4*)x;
    const float4* W14 = (const float4*)W1;

    #pragma unroll
    for (int p = 0; p < 8; ++p) {             // x tile: 64 rows x 32 granules (full K)
        int i = tid + p * 256;
        int r = i >> 5, g = i & 31;
        int gr = row0 + r; if (gr > N_NODES - 1) gr = N_NODES - 1;
        float4 v = x4[gr * 32 + g];
        xs[r * 32 + g] = make_uint2(pack2bf(v.x, v.y), pack2bf(v.z, v.w));
    }
    #pragma unroll
    for (int p = 0; p < 8; ++p) {             // W half 0: k 0..63 x 32 col-granules
        int i = tid + p * 256;
        int k = i >> 5, cg = i & 31;
        float4 v = W14[k * 32 + cg];
        ws[k * 32 + cg] = make_uint2(pack2bf(v.x, v.y), pack2bf(v.z, v.w));
    }
    __syncthreads();

    f32x2 acc[8][2];                          // [row][(c0,c1)|(c2,c3)]
    #pragma unroll
    for (int i = 0; i < 8; ++i) {
        acc[i][0] = (f32x2){0.f, 0.f};
        acc[i][1] = (f32x2){0.f, 0.f};
    }

    auto compute_half = [&](int g0) {         // 16 k-granules starting at xs granule g0
        for (int k4 = 0; k4 < 16; ++k4) {
            f32x2 aP[8][2];                   // [row][(k0,k1)|(k2,k3)]
            #pragma unroll
            for (int i = 0; i < 8; ++i) {
                uint2 q = xs[(tr * 8 + i) * 32 + g0 + k4];
                aP[i][0] = bf2x2(q.x);
                aP[i][1] = bf2x2(q.y);
            }
            #pragma unroll
            for (int kk = 0; kk < 4; ++kk) {
                uint2 qw = ws[(k4 * 4 + kk) * 32 + tc];
                f32x2 wlo = bf2x2(qw.x);
                f32x2 whi = bf2x2(qw.y);
                #pragma unroll
                for (int i = 0; i < 8; ++i) {
                    f32x2 ap = aP[i][kk >> 1];
                    if ((kk & 1) == 0) {
                        pkfma_lo(acc[i][0], ap, wlo);
                        pkfma_lo(acc[i][1], ap, whi);
                    } else {
                        pkfma_hi(acc[i][0], ap, wlo);
                        pkfma_hi(acc[i][1], ap, whi);
                    }
                }
            }
        }
    };

    compute_half(0);
    __syncthreads();                          // everyone done reading ws half 0
    #pragma unroll
    for (int p = 0; p < 8; ++p) {             // W half 1: k 64..127
        int i = tid + p * 256;
        int k = i >> 5, cg = i & 31;
        float4 v = W14[(k + 64) * 32 + cg];
        ws[k * 32 + cg] = make_uint2(pack2bf(v.x, v.y), pack2bf(v.z, v.w));
    }
    __syncthreads();
    compute_half(16);

    const int head = tc >> 2;
    const float4 as4 = ((const float4*)a_src)[tc];
    const float4 ad4 = ((const float4*)a_dst)[tc];
    #pragma unroll
    for (int i = 0; i < 8; ++i) {
        int r = row0 + tr * 8 + i;
        float s = acc[i][0].x * as4.x + acc[i][0].y * as4.y
                + acc[i][1].x * as4.z + acc[i][1].y * as4.w;
        float d = acc[i][0].x * ad4.x + acc[i][0].y * ad4.y
                + acc[i][1].x * ad4.z + acc[i][1].y * ad4.w;
        s += __shfl_xor(s, 1); s += __shfl_xor(s, 2);
        d += __shfl_xor(d, 1); d += __shfl_xor(d, 2);
        if (r < N_NODES) {
            ((uint2*)h1b)[r * 32 + tc] =
                make_uint2(pack2bf(acc[i][0].x, acc[i][0].y),
                           pack2bf(acc[i][1].x, acc[i][1].y));
            if ((tc & 3) == 0) {
                al_src[r * 8 + head] = s;
                al_dst[r * 8 + head] = d;
            }
        }
    }
}

// ---------------- fine CSR per bucket (1024 thr, wave-shuffle scan) ----------------
__global__ __launch_bounds__(1024) void k_csr_fine(const unsigned int* __restrict__ binned,
                                                   const int* __restrict__ cursor_g,
                                                   int* __restrict__ row_beg,
                                                   int* __restrict__ row_end,
                                                   int* __restrict__ csr) {
    __shared__ int cnt[256];
    __shared__ int cur[256];
    __shared__ int wsum[4];
    const int b = blockIdx.x, tid = threadIdx.x;
    const int start = b * CAP;
    const int nE    = cursor_g[b];
    if (tid < 256) cnt[tid] = 0;
    __syncthreads();
    for (int j = tid; j < nE; j += 1024)
        atomicAdd(&cnt[(binned[start + j] >> 18) & 255], 1);
    __syncthreads();
    int v = 0;
    if (tid < 256) v = cnt[tid];
    int sv = v;                                // wave-inclusive scan (64 lanes)
    #pragma unroll
    for (int off = 1; off < 64; off <<= 1) {
        int t = __shfl_up(sv, off);
        if ((tid & 63) >= off) sv += t;
    }
    if (tid < 256 && (tid & 63) == 63) wsum[tid >> 6] = sv;
    __syncthreads();
    if (tid < 256) {
        int w = tid >> 6;
        int add = 0;
        #pragma unroll
        for (int i = 0; i < 3; ++i) add += (i < w) ? wsum[i] : 0;
        int excl = sv + add - v;
        cur[tid] = excl;
        const int node = b * NPB + tid;
        if (tid < NPB && node < N_NODES) {
            row_beg[node] = start + excl;
            row_end[node] = start + excl + v;
        }
    }
    __syncthreads();
    for (int j = tid; j < nE; j += 1024) {
        unsigned int p = binned[start + j];
        int dl  = (p >> 18) & 255;
        int pos = start + atomicAdd(&cur[dl], 1);
        csr[pos] = (int)(p & 0x3FFFFu);
    }
}

// ---------------- agg1+gemm2 fused (R4 structure): W2 LDS staged once, single barrier ----------------
__global__ __launch_bounds__(256) void k_agg1g2(
    const unsigned short* __restrict__ h1b, const float* __restrict__ al_src,
    const float* __restrict__ al_dst, const int* __restrict__ row_beg,
    const int* __restrict__ row_end, const int* __restrict__ csr_src,
    const float* __restrict__ b1, const float* __restrict__ W2,
    const float* __restrict__ a_src2, const float* __restrict__ a_dst2,
    unsigned short* __restrict__ t2b, float* __restrict__ alS2,
    float* __restrict__ alD2)
{
    __shared__ __align__(16) float w2s[128 * 32];   // 16 KB, XOR-swizzled granules
    __shared__ __align__(16) float h2row[4][128];   // 2 KB, per-wave scratch
    const int tid  = threadIdx.x;
    const int wv   = tid >> 6;
    const int n    = blockIdx.x * 4 + wv;
    const int l    = tid & 63;
    const int slot = l >> 4;
    const int f2   = l & 15;
    const int head = f2 >> 1;
    const uint4* h1q = (const uint4*)h1b;    // 16 B = 8 bf16 feats

    // issue W2 staging loads, then per-node loads (overlap), then write+barrier
    float4 wreg[4];
    {
        const float4* W2v = (const float4*)W2;
        #pragma unroll
        for (int p = 0; p < 4; ++p) wreg[p] = W2v[tid + p * 256];
    }
    const float alD = al_dst[n * 8 + head];
    const int beg = row_beg[n], end = row_end[n];
    {
        float4* w2sv = (float4*)w2s;
        #pragma unroll
        for (int p = 0; p < 4; ++p) {
            int g = tid + p * 256;
            w2sv[g ^ ((g >> 7) & 7)] = wreg[p];
        }
    }
    __syncthreads();   // ONLY barrier: W2 staged; everything below is per-wave

    float denom = 0.f;
    f32x2 a01 = {0.f, 0.f}, a23 = {0.f, 0.f}, a45 = {0.f, 0.f}, a67 = {0.f, 0.f};

    if (slot == 0) {   // self loop
        float w = __expf(leaky(al_src[n * 8 + head] + alD));
        uint4 q = h1q[n * 16 + f2];
        denom = w;
        f32x2 wp = plow(w);
        pkfma_lo(a01, wp, bf2x2(q.x));
        pkfma_lo(a23, wp, bf2x2(q.y));
        pkfma_lo(a45, wp, bf2x2(q.z));
        pkfma_lo(a67, wp, bf2x2(q.w));
    }

    // guarded 4-wide gather: 4 independent csr loads -> 8 independent gathers per iter
    for (int j = beg + slot; j < end; j += 16) {
        const int e1 = (j + 4  < end) ? j + 4  : j;
        const int e2 = (j + 8  < end) ? j + 8  : j;
        const int e3 = (j + 12 < end) ? j + 12 : j;
        int s0 = csr_src[j];
        int s1 = csr_src[e1];
        int s2 = csr_src[e2];
        int s3 = csr_src[e3];
        float l0 = al_src[s0 * 8 + head];
        float l1 = al_src[s1 * 8 + head];
        float l2 = al_src[s2 * 8 + head];
        float l3 = al_src[s3 * 8 + head];
        uint4 q0 = h1q[s0 * 16 + f2];
        uint4 q1 = h1q[s1 * 16 + f2];
        uint4 q2 = h1q[s2 * 16 + f2];
        uint4 q3 = h1q[s3 * 16 + f2];
        float w0 = __expf(leaky(l0 + alD));
        float w1 = __expf(leaky(l1 + alD)); w1 = (e1 != j) ? w1 : 0.f;
        float w2 = __expf(leaky(l2 + alD)); w2 = (e2 != j) ? w2 : 0.f;
        float w3 = __expf(leaky(l3 + alD)); w3 = (e3 != j) ? w3 : 0.f;
        denom += (w0 + w1) + (w2 + w3);
        f32x2 wA; wA.x = w0; wA.y = w1;
        f32x2 wB; wB.x = w2; wB.y = w3;
        pkfma_lo(a01, wA, bf2x2(q0.x));
        pkfma_lo(a23, wA, bf2x2(q0.y));
        pkfma_lo(a45, wA, bf2x2(q0.z));
        pkfma_lo(a67, wA, bf2x2(q0.w));
        pkfma_hi(a01, wA, bf2x2(q1.x));
        pkfma_hi(a23, wA, bf2x2(q1.y));
        pkfma_hi(a45, wA, bf2x2(q1.z));
        pkfma_hi(a67, wA, bf2x2(q1.w));
        pkfma_lo(a01, wB, bf2x2(q2.x));
        pkfma_lo(a23, wB, bf2x2(q2.y));
        pkfma_lo(a45, wB, bf2x2(q2.z));
        pkfma_lo(a67, wB, bf2x2(q2.w));
        pkfma_hi(a01, wB, bf2x2(q3.x));
        pkfma_hi(a23, wB, bf2x2(q3.y));
        pkfma_hi(a45, wB, bf2x2(q3.z));
        pkfma_hi(a67, wB, bf2x2(q3.w));
    }

    #pragma unroll
    for (int off = 16; off <= 32; off <<= 1) {
        a01.x += __shfl_xor(a01.x, off); a01.y += __shfl_xor(a01.y, off);
        a23.x += __shfl_xor(a23.x, off); a23.y += __shfl_xor(a23.y, off);
        a45.x += __shfl_xor(a45.x, off); a45.y += __shfl_xor(a45.y, off);
        a67.x += __shfl_xor(a67.x, off); a67.y += __shfl_xor(a67.y, off);
        denom += __shfl_xor(denom, off);
    }

    // h2 row (bias + ELU) — all lanes compute; slot 0 writes to per-wave LDS
    {
        const float4 bA = ((const float4*)b1)[f2 * 2];
        const float4 bB = ((const float4*)b1)[f2 * 2 + 1];
        float inv = 1.f / denom;
        float o[8];
        o[0] = a01.x * inv + bA.x; o[1] = a01.y * inv + bA.y;
        o[2] = a23.x * inv + bA.z; o[3] = a23.y * inv + bA.w;
        o[4] = a45.x * inv + bB.x; o[5] = a45.y * inv + bB.y;
        o[6] = a67.x * inv + bB.z; o[7] = a67.y * inv + bB.w;
        #pragma unroll
        for (int i = 0; i < 8; ++i) o[i] = o[i] > 0.f ? o[i] : __expf(o[i]) - 1.f;
        if (slot == 0) {
            *(float4*)&h2row[wv][f2 * 8]     = make_float4(o[0], o[1], o[2], o[3]);
            *(float4*)&h2row[wv][f2 * 8 + 4] = make_float4(o[4], o[5], o[6], o[7]);
        }
    }
    // no barrier: h2row[wv] written and read by the same wave

    // fused gemm2: lane = (kg = l>>3: k-range of 16, cg = l&7: classes cg*4..+3)
    const int cg = l & 7;
    const int kg = l >> 3;
    const float* hrow = h2row[wv];
    f32x4 hv[4];
    #pragma unroll
    for (int t = 0; t < 4; ++t)
        hv[t] = *(const f32x4*)&hrow[kg * 16 + t * 4];
    const f32x4* w2v = (const f32x4*)w2s;
    f32x2 s01 = {0.f, 0.f}, s23 = {0.f, 0.f};
    #pragma unroll
    for (int t = 0; t < 4; ++t) {
        f32x2 hlo = lo2(hv[t]);
        f32x2 hhi = hi2(hv[t]);
        #pragma unroll
        for (int u = 0; u < 4; ++u) {
            const int k = kg * 16 + t * 4 + u;
            f32x4 w4 = w2v[(k * 8 + cg) ^ kg];      // ds_read_b128
            f32x2 wlo = lo2(w4);
            f32x2 whi = hi2(w4);
            if (u == 0)      { pkfma_lo(s01, hlo, wlo); pkfma_lo(s23, hlo, whi); }
            else if (u == 1) { pkfma_hi(s01, hlo, wlo); pkfma_hi(s23, hlo, whi); }
            else if (u == 2) { pkfma_lo(s01, hhi, wlo); pkfma_lo(s23, hhi, whi); }
            else             { pkfma_hi(s01, hhi, wlo); pkfma_hi(s23, hhi, whi); }
        }
    }
    #pragma unroll
    for (int off = 8; off <= 32; off <<= 1) {        // reduce over kg (bits 3..5)
        s01.x += __shfl_xor(s01.x, off); s01.y += __shfl_xor(s01.y, off);
        s23.x += __shfl_xor(s23.x, off); s23.y += __shfl_xor(s23.y, off);
    }

    if (l < 8)                                       // kg==0 lanes: 8 x 8 B = full t2 row
        ((uint2*)t2b)[n * 8 + cg] =
            make_uint2(pack2bf(s01.x, s01.y), pack2bf(s23.x, s23.y));

    const float4 as2 = ((const float4*)a_src2)[cg];
    const float4 ad2 = ((const float4*)a_dst2)[cg];
    float s2 = s01.x * as2.x + s01.y * as2.y + s23.x * as2.z + s23.y * as2.w;
    float d2 = s01.x * ad2.x + s01.y * ad2.y + s23.x * ad2.z + s23.y * ad2.w;
    #pragma unroll
    for (int off = 1; off <= 4; off <<= 1) {         // reduce over cg (bits 0..2)
        s2 += __shfl_xor(s2, off);
        d2 += __shfl_xor(d2, off);
    }
    if (l == 0) {
        alS2[n] = s2;
        alD2[n] = d2;
    }
}

// ---------------- agg2: wave/node, 8 slots x 8 lanes x 8B, guarded 4-wide, pk_fma ----------------
__global__ __launch_bounds__(256) void k_agg2(
    const unsigned short* __restrict__ t2b, const float* __restrict__ al_src,
    const float* __restrict__ al_dst, const int* __restrict__ row_beg,
    const int* __restrict__ row_end, const int* __restrict__ csr_src,
    const float* __restrict__ b2, float* __restrict__ out)
{
    const int n = blockIdx.x * 4 + (threadIdx.x >> 6);
    const int l = threadIdx.x & 63;
    const int slot = l >> 3;          // 8 edge slots
    const int f4   = l & 7;           // 4 classes per lane (uint2 of bf16x2)
    const uint2* t2u = (const uint2*)t2b;   // 8 B = 4 bf16

    const float alD = al_dst[n];
    const int beg = row_beg[n], end = row_end[n];
    float denom = 0.f;
    f32x2 a01 = {0.f, 0.f}, a23 = {0.f, 0.f};
    if (slot == 0) {                  // self loop
        float w = __expf(leaky(al_src[n] + alD));
        uint2 q = t2u[n * 8 + f4];
        denom = w;
        f32x2 wp = plow(w);
        pkfma_lo(a01, wp, bf2x2(q.x));
        pkfma_lo(a23, wp, bf2x2(q.y));
    }
    for (int j = beg + slot; j < end; j += 32) {   // guarded 4-wide
        const int e1 = (j + 8  < end) ? j + 8  : j;
        const int e2 = (j + 16 < end) ? j + 16 : j;
        const int e3 = (j + 24 < end) ? j + 24 : j;
        int s0 = csr_src[j];
        int s1 = csr_src[e1];
        int s2 = csr_src[e2];
        int s3 = csr_src[e3];
        float l0 = al_src[s0];
        float l1 = al_src[s1];
        float l2 = al_src[s2];
        float l3 = al_src[s3];
        uint2 q0 = t2u[s0 * 8 + f4];
        uint2 q1 = t2u[s1 * 8 + f4];
        uint2 q2 = t2u[s2 * 8 + f4];
        uint2 q3 = t2u[s3 * 8 + f4];
        float w0 = __expf(leaky(l0 + alD));
        float w1 = __expf(leaky(l1 + alD)); w1 = (e1 != j) ? w1 : 0.f;
        float w2 = __expf(leaky(l2 + alD)); w2 = (e2 != j) ? w2 : 0.f;
        float w3 = __expf(leaky(l3 + alD)); w3 = (e3 != j) ? w3 : 0.f;
        denom += (w0 + w1) + (w2 + w3);
        f32x2 wA; wA.x = w0; wA.y = w1;
        f32x2 wB; wB.x = w2; wB.y = w3;
        pkfma_lo(a01, wA, bf2x2(q0.x));
        pkfma_lo(a23, wA, bf2x2(q0.y));
        pkfma_hi(a01, wA, bf2x2(q1.x));
        pkfma_hi(a23, wA, bf2x2(q1.y));
        pkfma_lo(a01, wB, bf2x2(q2.x));
        pkfma_lo(a23, wB, bf2x2(q2.y));
        pkfma_hi(a01, wB, bf2x2(q3.x));
        pkfma_hi(a23, wB, bf2x2(q3.y));
    }
    // reduce over the 8 slots (lane bits 3,4,5)
    #pragma unroll
    for (int off = 8; off <= 32; off <<= 1) {
        a01.x += __shfl_xor(a01.x, off); a01.y += __shfl_xor(a01.y, off);
        a23.x += __shfl_xor(a23.x, off); a23.y += __shfl_xor(a23.y, off);
        denom += __shfl_xor(denom, off);
    }

    const float4 bb = ((const float4*)b2)[f4];
    float inv = 1.f / denom;
    float o0 = a01.x * inv + bb.x;
    float o1 = a01.y * inv + bb.y;
    float o2 = a23.x * inv + bb.z;
    float o3 = a23.y * inv + bb.w;
    // log_softmax over 32 classes (8 lanes x 4 classes; lane bits 0..2)
    float m = fmaxf(fmaxf(o0, o1), fmaxf(o2, o3));
    for (int off = 1; off <= 4; off <<= 1) m = fmaxf(m, __shfl_xor(m, off));
    float ssum = __expf(o0 - m) + __expf(o1 - m) + __expf(o2 - m) + __expf(o3 - m);
    for (int off = 1; off <= 4; off <<= 1) ssum += __shfl_xor(ssum, off);
    float lg = m + __logf(ssum);
    if (slot == 0)
        ((float4*)out)[n * 8 + f4] = make_float4(o0 - lg, o1 - lg, o2 - lg, o3 - lg);
}

extern "C" void kernel_launch(void* const* d_in, const int* in_sizes, int n_in,
                              void* d_out, int out_size, void* d_ws, size_t ws_size,
                              hipStream_t stream) {
    const float* x      = (const float*)d_in[0];
    const int*   src    = (const int*)d_in[1];
    const int*   dst    = (const int*)d_in[2];
    const float* W1     = (const float*)d_in[3];
    const float* a_src1 = (const float*)d_in[4];
    const float* a_dst1 = (const float*)d_in[5];
    const float* b1     = (const float*)d_in[6];
    const float* W2     = (const float*)d_in[7];
    const float* a_src2 = (const float*)d_in[8];
    const float* a_dst2 = (const float*)d_in[9];
    const float* b2     = (const float*)d_in[10];
    float* out = (float*)d_out;

    char* ws = (char*)d_ws;
    size_t off = 0;
    auto alloc = [&](size_t bytes) {
        void* p = ws + off;
        off += (bytes + 255) & ~(size_t)255;
        return p;
    };
    unsigned short* h1b = (unsigned short*)alloc((size_t)N_NODES * 128 * 2);
    unsigned short* t2b = (unsigned short*)alloc((size_t)N_NODES * 32 * 2);
    float* alS1    = (float*)alloc((size_t)N_NODES * 8 * 4);
    float* alD1    = (float*)alloc((size_t)N_NODES * 8 * 4);
    float* alS2    = (float*)alloc((size_t)N_NODES * 4);
    float* alD2    = (float*)alloc((size_t)N_NODES * 4);
    int*   row_beg = (int*)alloc((size_t)N_NODES * 4);
    int*   row_end = (int*)alloc((size_t)N_NODES * 4);
    int*   csr     = (int*)alloc((size_t)NBKT * CAP * 4);      // 4 MB padded
    unsigned int* binned = (unsigned int*)alloc((size_t)NBKT * CAP * 4);  // 4 MB
    int*   cursor  = (int*)alloc((size_t)NBKT * 4);
    (void)ws_size; (void)in_sizes; (void)n_in; (void)out_size;

    hipMemsetAsync(cursor, 0, (size_t)NBKT * 4, stream);
    k_bin_gemm1<<<NBKT + G1BLK, 256, 0, stream>>>(
        src, dst, cursor, binned,
        x, W1, a_src1, a_dst1, h1b, alS1, alD1);
    k_csr_fine<<<NBKT, 1024, 0, stream>>>(binned, cursor, row_beg, row_end, csr);
    k_agg1g2<<<N_NODES / 4, 256, 0, stream>>>(
        h1b, alS1, alD1, row_beg, row_end, csr,
        b1, W2, a_src2, a_dst2, t2b, alS2, alD2);
    k_agg2<<<N_NODES / 4, 256, 0, stream>>>(t2b, alS2, alD2, row_beg, row_end, csr, b2, out);
}